// Round 2
// baseline (1145.924 us; speedup 1.0000x reference)
//
#include <hip/hip_runtime.h>

#define BB 16
#define SS 8192
#define DD 256

// ---------------------------------------------------------------------------
// Pass 1: raw second moment  sumxx[b][d][e] = sum_s x[b,s,d]*x[b,s,e]
//         and column sums    sumx[b][d]     = sum_s x[b,s,d]
// Grid: (16 s-chunks of 512 rows, 16 batches), 1024 threads.
// 8x8 micro-tile per thread with contiguous float4 fragment reads.
// ---------------------------------------------------------------------------
__global__ __launch_bounds__(1024) void moment_kernel(const float* __restrict__ x,
                                                      float* __restrict__ sumxx,
                                                      float* __restrict__ sumx) {
    const int chunk = blockIdx.x;   // 0..15 -> 512 rows each
    const int b     = blockIdx.y;   // 0..15
    const float* xb = x + ((size_t)b * SS + (size_t)chunk * 512) * DD;

    __shared__ float tile[64 * 256];   // 64 KB

    const int tid = threadIdx.x;
    const int ty  = tid >> 5;   // 0..31 -> rows ty*8..ty*8+7
    const int tx  = tid & 31;   // 0..31 -> cols tx*8..tx*8+7

    float acc[8][8];
#pragma unroll
    for (int i = 0; i < 8; ++i)
#pragma unroll
        for (int j = 0; j < 8; ++j) acc[i][j] = 0.0f;
    float colsum = 0.0f;

    for (int st = 0; st < 8; ++st) {
        const float4* src = (const float4*)(xb + (size_t)st * 64 * 256);
        float4* dst = (float4*)tile;
#pragma unroll
        for (int t = 0; t < 4; ++t) dst[tid + t * 1024] = src[tid + t * 1024];
        __syncthreads();

        if (tid < 256) {
            for (int r = 0; r < 64; ++r) colsum += tile[r * 256 + tid];
        }

        for (int r = 0; r < 64; ++r) {
            float a[8], bb2[8];
            *(float4*)&a[0]   = *(const float4*)&tile[r * 256 + ty * 8];
            *(float4*)&a[4]   = *(const float4*)&tile[r * 256 + ty * 8 + 4];
            *(float4*)&bb2[0] = *(const float4*)&tile[r * 256 + tx * 8];
            *(float4*)&bb2[4] = *(const float4*)&tile[r * 256 + tx * 8 + 4];
#pragma unroll
            for (int i = 0; i < 8; ++i)
#pragma unroll
                for (int j = 0; j < 8; ++j) acc[i][j] += a[i] * bb2[j];
        }
        __syncthreads();
    }

    float* sx = sumxx + (size_t)b * DD * DD;
#pragma unroll
    for (int i = 0; i < 8; ++i)
#pragma unroll
        for (int j = 0; j < 8; ++j)
            atomicAdd(&sx[(size_t)(ty * 8 + i) * DD + (tx * 8 + j)], acc[i][j]);
    if (tid < 256) atomicAdd(&sumx[b * DD + tid], colsum);
}

// ---------------------------------------------------------------------------
// Pass 2: per-batch mean, trace(sigma), rsqrt(tr), 1/tr.
// trbuf layout: [0..15]=tr, [16..31]=rsqrt(tr), [32..47]=1/tr
// ---------------------------------------------------------------------------
__global__ __launch_bounds__(256) void stats_kernel(const float* __restrict__ sumxx,
                                                    const float* __restrict__ sumx,
                                                    float* __restrict__ m,
                                                    float* __restrict__ trbuf) {
    const int b = blockIdx.x;
    const int d = threadIdx.x;
    const float mean = sumx[b * DD + d] * (1.0f / (float)SS);
    m[b * DD + d] = mean;
    const float diag =
        (sumxx[(size_t)b * DD * DD + (size_t)d * DD + d] - (float)SS * mean * mean) *
        (1.0f / (float)(SS - 1));
    __shared__ float red[256];
    red[d] = diag;
    __syncthreads();
    for (int off = 128; off > 0; off >>= 1) {
        if (d < off) red[d] += red[d + off];
        __syncthreads();
    }
    if (d == 0) {
        const float tr = red[0];
        trbuf[b]      = tr;
        trbuf[16 + b] = rsqrtf(tr);
        trbuf[32 + b] = 1.0f / tr;
    }
}

// ---------------------------------------------------------------------------
// Pass 3: sigma_n[b][d][e] = ((sumxx - S*m_d*m_e)/(S-1)) / tr
// ---------------------------------------------------------------------------
__global__ __launch_bounds__(256) void sigman_kernel(const float* __restrict__ sumxx,
                                                     const float* __restrict__ m,
                                                     const float* __restrict__ trbuf,
                                                     float* __restrict__ Xa) {
    const int b = blockIdx.y;
    const int d = blockIdx.x;
    const int e = threadIdx.x;
    const float itr = trbuf[32 + b];
    const float md = m[b * DD + d];
    const float me = m[b * DD + e];
    const size_t idx = (size_t)b * DD * DD + (size_t)d * DD + e;
    Xa[idx] = (sumxx[idx] - (float)SS * md * me) * (1.0f / (float)(SS - 1)) * itr;
}

// ---------------------------------------------------------------------------
// Batched 256x256x256 matmul: C[b] = opA(A[b]) @ opB(B[b])
// REQUIRES A symmetric (true: every NS iterate is a polynomial of sigma_n),
// which lets us stage A k-major straight from global (coalesced), so the
// inner-loop fragment read As[kk][ty*4] is A[m0+ty*4+i][k0+kk] as intended.
// op==1 applies W = 1.5*I - 0.5*X at load.
// ---------------------------------------------------------------------------
template <int TA, int TB>
__global__ __launch_bounds__(256) void bmm_ns(const float* __restrict__ A,
                                              const float* __restrict__ B,
                                              float* __restrict__ C) {
    const int b  = blockIdx.y;
    const int m0 = (blockIdx.x >> 2) * 64;
    const int n0 = (blockIdx.x & 3) * 64;
    const float* Ab = A + (size_t)b * DD * DD;
    const float* Bb = B + (size_t)b * DD * DD;

    __shared__ float As[64][64];   // As[kk][mm] = A[m0+mm][k0+kk]
    __shared__ float Bs[64][64];   // Bs[kk][nn] = B[k0+kk][n0+nn]

    const int tid  = threadIdx.x;
    const int ty   = tid >> 4;         // 0..15
    const int tx   = tid & 15;         // 0..15
    const int lrow = tid >> 4;         // 0..15
    const int lcol = (tid & 15) * 4;   // 0,4,..,60

    float acc[4][4];
#pragma unroll
    for (int i = 0; i < 4; ++i)
#pragma unroll
        for (int j = 0; j < 4; ++j) acc[i][j] = 0.0f;

    for (int k0 = 0; k0 < DD; k0 += 64) {
#pragma unroll
        for (int t = 0; t < 4; ++t) {
            const int row = lrow + t * 16;
            // A staged k-major using symmetry: load A[k0+row][m0+lcol..+3]
            float4 va = *(const float4*)&Ab[(size_t)(k0 + row) * DD + m0 + lcol];
            if (TA == 1) {
                const int gk = k0 + row, gm = m0 + lcol;
                va.x = ((gk == gm + 0) ? 1.5f : 0.0f) - 0.5f * va.x;
                va.y = ((gk == gm + 1) ? 1.5f : 0.0f) - 0.5f * va.y;
                va.z = ((gk == gm + 2) ? 1.5f : 0.0f) - 0.5f * va.z;
                va.w = ((gk == gm + 3) ? 1.5f : 0.0f) - 0.5f * va.w;
            }
            *(float4*)&As[row][lcol] = va;

            float4 vb = *(const float4*)&Bb[(size_t)(k0 + row) * DD + n0 + lcol];
            if (TB == 1) {
                const int gk = k0 + row, gn = n0 + lcol;
                vb.x = ((gk == gn + 0) ? 1.5f : 0.0f) - 0.5f * vb.x;
                vb.y = ((gk == gn + 1) ? 1.5f : 0.0f) - 0.5f * vb.y;
                vb.z = ((gk == gn + 2) ? 1.5f : 0.0f) - 0.5f * vb.z;
                vb.w = ((gk == gn + 3) ? 1.5f : 0.0f) - 0.5f * vb.w;
            }
            *(float4*)&Bs[row][lcol] = vb;
        }
        __syncthreads();
#pragma unroll 8
        for (int kk = 0; kk < 64; ++kk) {
            const float4 av = *(const float4*)&As[kk][ty * 4];
            const float4 bv = *(const float4*)&Bs[kk][tx * 4];
            const float a4[4] = {av.x, av.y, av.z, av.w};
            const float b4[4] = {bv.x, bv.y, bv.z, bv.w};
#pragma unroll
            for (int i = 0; i < 4; ++i)
#pragma unroll
                for (int j = 0; j < 4; ++j) acc[i][j] += a4[i] * b4[j];
        }
        __syncthreads();
    }

    float* Cb = C + (size_t)b * DD * DD;
#pragma unroll
    for (int i = 0; i < 4; ++i) {
        float4 v = make_float4(acc[i][0], acc[i][1], acc[i][2], acc[i][3]);
        *(float4*)&Cb[(size_t)(m0 + ty * 4 + i) * DD + n0 + tx * 4] = v;
    }
}

// ---------------------------------------------------------------------------
// Final: out[b,s,e] = sum_d (x[b,s,d]-m[b,d]) * P[b,d,e] * rsqrt(tr[b])
// 128x128 tile, BK=16, 8x8 micro-tile, 256 threads.
// A transposed into LDS at staging (pad 132 -> conflict-free scalar stores).
// ---------------------------------------------------------------------------
__global__ __launch_bounds__(256) void apply_kernel(const float* __restrict__ x,
                                                    const float* __restrict__ P,
                                                    const float* __restrict__ m,
                                                    const float* __restrict__ trbuf,
                                                    float* __restrict__ out) {
    const int b  = blockIdx.z;
    const int m0 = blockIdx.x * 128;
    const int n0 = blockIdx.y * 128;
    const float rs = trbuf[16 + b];
    const float* xb = x + (size_t)b * SS * DD;
    const float* Pb = P + (size_t)b * DD * DD;
    const float* mb = m + b * DD;
    float* ob = out + (size_t)b * SS * DD;

    __shared__ float As[16][132];   // As[k][m] = xn[m0+m][k0+k]  (pad 132)
    __shared__ float Bs[16][128];   // Bs[k][n] = wm[k0+k][n0+n]

    const int tid = threadIdx.x;
    const int ty  = tid >> 4;   // 0..15 -> rows ty*8..+7
    const int tx  = tid & 15;   // 0..15 -> cols tx*8..+7

    float acc[8][8];
#pragma unroll
    for (int i = 0; i < 8; ++i)
#pragma unroll
        for (int j = 0; j < 8; ++j) acc[i][j] = 0.0f;

    for (int k0 = 0; k0 < DD; k0 += 16) {
        // stage A (128 rows x 16 k), transposed into LDS
#pragma unroll
        for (int t = 0; t < 2; ++t) {
            const int f   = tid + t * 256;
            const int row = f >> 2;        // 0..127
            const int c   = (f & 3) * 4;   // 0,4,8,12
            float4 va = *(const float4*)&xb[(size_t)(m0 + row) * DD + k0 + c];
            const float4 mv = *(const float4*)&mb[k0 + c];
            va.x -= mv.x; va.y -= mv.y; va.z -= mv.z; va.w -= mv.w;
            As[c + 0][row] = va.x;
            As[c + 1][row] = va.y;
            As[c + 2][row] = va.z;
            As[c + 3][row] = va.w;
        }
        // stage B (16 k x 128 cols), fold in rsqrt(tr)
#pragma unroll
        for (int t = 0; t < 2; ++t) {
            const int f  = tid + t * 256;
            const int kk = f >> 5;         // 0..15
            const int cc = (f & 31) * 4;   // 0..124
            float4 vb = *(const float4*)&Pb[(size_t)(k0 + kk) * DD + n0 + cc];
            vb.x *= rs; vb.y *= rs; vb.z *= rs; vb.w *= rs;
            *(float4*)&Bs[kk][cc] = vb;
        }
        __syncthreads();
#pragma unroll
        for (int kk = 0; kk < 16; ++kk) {
            float a8[8], b8[8];
            *(float4*)&a8[0] = *(const float4*)&As[kk][ty * 8];
            *(float4*)&a8[4] = *(const float4*)&As[kk][ty * 8 + 4];
            *(float4*)&b8[0] = *(const float4*)&Bs[kk][tx * 8];
            *(float4*)&b8[4] = *(const float4*)&Bs[kk][tx * 8 + 4];
#pragma unroll
            for (int i = 0; i < 8; ++i)
#pragma unroll
                for (int j = 0; j < 8; ++j) acc[i][j] += a8[i] * b8[j];
        }
        __syncthreads();
    }

#pragma unroll
    for (int i = 0; i < 8; ++i) {
        float* orow = &ob[(size_t)(m0 + ty * 8 + i) * DD + n0 + tx * 8];
        *(float4*)&orow[0] = make_float4(acc[i][0], acc[i][1], acc[i][2], acc[i][3]);
        *(float4*)&orow[4] = make_float4(acc[i][4], acc[i][5], acc[i][6], acc[i][7]);
    }
}

extern "C" void kernel_launch(void* const* d_in, const int* in_sizes, int n_in,
                              void* d_out, int out_size, void* d_ws, size_t ws_size,
                              hipStream_t stream) {
    const float* x = (const float*)d_in[0];
    float* out = (float*)d_out;
    float* ws = (float*)d_ws;

    const size_t MAT = (size_t)BB * DD * DD;   // 1,048,576 floats (4 MB)
    float* sumxx = ws;
    float* sumx  = sumxx + MAT;        // 4096
    float* m     = sumx + BB * DD;     // 4096
    float* trbuf = m + BB * DD;        // 64 (tr | rsqrt(tr) | 1/tr)
    float* Xa    = trbuf + 64;
    float* Xb    = Xa + MAT;
    float* T     = Xb + MAT;
    float* Pa    = T + MAT;
    float* Pb    = Pa + MAT;
    // total: ~25.2 MB of workspace

    hipMemsetAsync(sumxx, 0, (MAT + (size_t)BB * DD) * sizeof(float), stream);

    moment_kernel<<<dim3(16, 16), 1024, 0, stream>>>(x, sumxx, sumx);
    stats_kernel<<<16, 256, 0, stream>>>(sumxx, sumx, m, trbuf);
    sigman_kernel<<<dim3(256, 16), 256, 0, stream>>>(sumxx, m, trbuf, Xa);

    // Newton-Schulz, commutative form: X0 = sigma_n (in Xa), P1 = W0 (implicit)
    bmm_ns<1, 1><<<dim3(16, 16), 256, 0, stream>>>(Xa, Xa, T);   // T  = W0^2
    bmm_ns<0, 0><<<dim3(16, 16), 256, 0, stream>>>(Xa, T, Xb);   // X1 = X0*W0^2
    bmm_ns<1, 1><<<dim3(16, 16), 256, 0, stream>>>(Xa, Xb, Pa);  // P2 = W0*W1
    bmm_ns<1, 1><<<dim3(16, 16), 256, 0, stream>>>(Xb, Xb, T);   // T  = W1^2
    bmm_ns<0, 0><<<dim3(16, 16), 256, 0, stream>>>(Xb, T, Xa);   // X2 = X1*W1^2
    bmm_ns<0, 1><<<dim3(16, 16), 256, 0, stream>>>(Pa, Xa, Pb);  // P3 = P2*W2
    bmm_ns<1, 1><<<dim3(16, 16), 256, 0, stream>>>(Xa, Xa, T);   // T  = W2^2
    bmm_ns<0, 0><<<dim3(16, 16), 256, 0, stream>>>(Xa, T, Xb);   // X3 = X2*W2^2
    bmm_ns<0, 1><<<dim3(16, 16), 256, 0, stream>>>(Pb, Xb, Pa);  // P4 = P3*W3

    apply_kernel<<<dim3(64, 2, 16), 256, 0, stream>>>(x, Pa, m, trbuf, out);
}

// Round 3
// 504.784 us; speedup vs baseline: 2.2701x; 2.2701x over previous
//
#include <hip/hip_runtime.h>

#define BB 16
#define SS 8192
#define DD 256

typedef __attribute__((ext_vector_type(8))) short bf16x8;
typedef __attribute__((ext_vector_type(4))) short bf16x4;
typedef __attribute__((ext_vector_type(4))) float f32x4;

union frag_u { bf16x8 v8; bf16x4 v4[2]; };

__device__ __forceinline__ unsigned short f2bf(float f) {
    union { float f; unsigned u; } v; v.f = f;
    unsigned r = v.u + 0x7FFFu + ((v.u >> 16) & 1u);   // round-to-nearest-even
    return (unsigned short)(r >> 16);
}
__device__ __forceinline__ unsigned pack2(float a, float b) {
    return (unsigned)f2bf(a) | ((unsigned)f2bf(b) << 16);
}
__device__ __forceinline__ bf16x8 ldfrag(const unsigned short* p) {
    frag_u f;
    f.v4[0] = *(const bf16x4*)(p);       // ds_read_b64
    f.v4[1] = *(const bf16x4*)(p + 4);   // ds_read_b64
    return f.v8;
}

#define LTS 36   // LDS row stride in bf16 elems (32 + 4 pad -> 72B, odd*8: spreads banks)

// ---------------------------------------------------------------------------
// moment: partial[kc][b][d][e] = sum_{s in kc-chunk} x[b,s,d]*x[b,s,e]  (bf16 MFMA)
// plus column sums (half==0 blocks only). Grid (8 kc, 2 half, 16 b) x 256.
// LDS slab Lt holds X^T for a 32-row s-chunk: Lt[prow(d)][s], prow = (d&3)*64+(d>>2)
// (permutation makes transpose-staging writes ~4-way instead of 16-way).
// Both MFMA operands (A rows = m-range, B rows = n-range) read from the slab.
// ---------------------------------------------------------------------------
__global__ __launch_bounds__(256) void moment_kernel(const float* __restrict__ x,
                                                     float* __restrict__ partial,
                                                     float* __restrict__ sumx) {
    const int kc   = blockIdx.x;   // 0..7  : k-chunk of 1024 s-rows
    const int half = blockIdx.y;   // 0..1  : which 128 output rows
    const int b    = blockIdx.z;
    const float* xb = x + ((size_t)b * SS + (size_t)kc * 1024) * DD;

    __shared__ unsigned short Lt[256 * LTS];   // 18.4 KB
    __shared__ float csh[4 * 256];             // 4 KB

    const int tid  = threadIdx.x;
    const int wave = tid >> 6;
    const int lane = tid & 63;
    const int lc   = lane & 15;
    const int lq   = lane >> 4;

    const int mrow0 = half * 128 + (wave & 1) * 64;   // 4 m-tiles of 16
    const int nrow0 = (wave >> 1) * 128;              // 8 n-tiles of 16

    const int sl = tid >> 6;   // 0..3 : s-subrange
    const int dg = tid & 63;   // d-group (4 cols)

    f32x4 acc[4][8];
#pragma unroll
    for (int mi = 0; mi < 4; ++mi)
#pragma unroll
        for (int ni = 0; ni < 8; ++ni) acc[mi][ni] = (f32x4){0.f, 0.f, 0.f, 0.f};
    float cs[4] = {0.f, 0.f, 0.f, 0.f};

    for (int step = 0; step < 32; ++step) {
        const float* src = xb + (size_t)step * 32 * DD;
        float4 v[8];
#pragma unroll
        for (int i = 0; i < 8; ++i)
            v[i] = *(const float4*)(src + (size_t)(sl * 8 + i) * DD + dg * 4);
        if (half == 0) {
#pragma unroll
            for (int i = 0; i < 8; ++i) {
                cs[0] += v[i].x; cs[1] += v[i].y; cs[2] += v[i].z; cs[3] += v[i].w;
            }
        }
        __syncthreads();   // previous step's fragment reads complete
        const float* vp = (const float*)v;
#pragma unroll
        for (int j = 0; j < 4; ++j) {
            // d = dg*4+j  ->  prow = j*64+dg
            unsigned short* row = &Lt[(j * 64 + dg) * LTS + sl * 8];
            *(unsigned*)&row[0] = pack2(vp[0 * 4 + j], vp[1 * 4 + j]);
            *(unsigned*)&row[2] = pack2(vp[2 * 4 + j], vp[3 * 4 + j]);
            *(unsigned*)&row[4] = pack2(vp[4 * 4 + j], vp[5 * 4 + j]);
            *(unsigned*)&row[6] = pack2(vp[6 * 4 + j], vp[7 * 4 + j]);
        }
        __syncthreads();

        bf16x8 af[4], bfr[8];
#pragma unroll
        for (int mi = 0; mi < 4; ++mi) {
            const int d = mrow0 + mi * 16 + lc;
            af[mi] = ldfrag(&Lt[(((d & 3) << 6) + (d >> 2)) * LTS + lq * 8]);
        }
#pragma unroll
        for (int ni = 0; ni < 8; ++ni) {
            const int d = nrow0 + ni * 16 + lc;
            bfr[ni] = ldfrag(&Lt[(((d & 3) << 6) + (d >> 2)) * LTS + lq * 8]);
        }
#pragma unroll
        for (int mi = 0; mi < 4; ++mi)
#pragma unroll
            for (int ni = 0; ni < 8; ++ni)
                acc[mi][ni] = __builtin_amdgcn_mfma_f32_16x16x32_bf16(
                    af[mi], bfr[ni], acc[mi][ni], 0, 0, 0);
    }

    float* pp = partial + (size_t)(kc * 16 + b) * DD * DD;
#pragma unroll
    for (int mi = 0; mi < 4; ++mi)
#pragma unroll
        for (int ni = 0; ni < 8; ++ni) {
            const int row = mrow0 + mi * 16 + lq * 4;
            const int col = nrow0 + ni * 16 + lc;
#pragma unroll
            for (int r = 0; r < 4; ++r)
                pp[(size_t)(row + r) * DD + col] = acc[mi][ni][r];
        }

    if (half == 0) {
        __syncthreads();
        csh[sl * 256 + dg * 4 + 0] = cs[0];
        csh[sl * 256 + dg * 4 + 1] = cs[1];
        csh[sl * 256 + dg * 4 + 2] = cs[2];
        csh[sl * 256 + dg * 4 + 3] = cs[3];
        __syncthreads();
        if (tid < 256) {
            float t0 = csh[tid] + csh[256 + tid] + csh[512 + tid] + csh[768 + tid];
            atomicAdd(&sumx[b * DD + tid], t0);
        }
    }
}

// ---------------------------------------------------------------------------
// stats: mean, trace(sigma), rsqrt(tr), 1/tr. trbuf: [0..15]=tr,[16..31]=rsqrt,[32..47]=1/tr
// ---------------------------------------------------------------------------
__global__ __launch_bounds__(256) void stats_kernel(const float* __restrict__ partial,
                                                    const float* __restrict__ sumx,
                                                    float* __restrict__ m,
                                                    float* __restrict__ trbuf) {
    const int b = blockIdx.x;
    const int d = threadIdx.x;
    const float mean = sumx[b * DD + d] * (1.0f / (float)SS);
    m[b * DD + d] = mean;
    float ds = 0.f;
#pragma unroll
    for (int kc = 0; kc < 8; ++kc)
        ds += partial[((size_t)(kc * 16 + b) * DD + d) * DD + d];
    const float diag = (ds - (float)SS * mean * mean) * (1.0f / (float)(SS - 1));
    __shared__ float red[256];
    red[d] = diag;
    __syncthreads();
    for (int off = 128; off > 0; off >>= 1) {
        if (d < off) red[d] += red[d + off];
        __syncthreads();
    }
    if (d == 0) {
        const float tr = red[0];
        trbuf[b]      = tr;
        trbuf[16 + b] = rsqrtf(tr);
        trbuf[32 + b] = 1.0f / tr;
    }
}

// ---------------------------------------------------------------------------
// sigman: Xa[b][d][e] = ((sum_kc partial - S*m_d*m_e)/(S-1)) / tr
// ---------------------------------------------------------------------------
__global__ __launch_bounds__(256) void sigman_kernel(const float* __restrict__ partial,
                                                     const float* __restrict__ m,
                                                     const float* __restrict__ trbuf,
                                                     float* __restrict__ Xa) {
    const int b = blockIdx.y;
    const int d = blockIdx.x;
    const int e = threadIdx.x;
    const float itr = trbuf[32 + b];
    const float md = m[b * DD + d];
    const float me = m[b * DD + e];
    float s = 0.f;
#pragma unroll
    for (int kc = 0; kc < 8; ++kc)
        s += partial[((size_t)(kc * 16 + b) * DD + d) * DD + e];
    Xa[(size_t)b * DD * DD + (size_t)d * DD + e] =
        (s - (float)SS * md * me) * (1.0f / (float)(SS - 1)) * itr;
}

// ---------------------------------------------------------------------------
// Batched 256^3 fp32 matmul (NS iterates are symmetric polys of sigma_n; A staged
// k-major via symmetry). op==1 applies W = 1.5*I - 0.5*X at load.
// ---------------------------------------------------------------------------
template <int TA, int TB>
__global__ __launch_bounds__(256) void bmm_ns(const float* __restrict__ A,
                                              const float* __restrict__ B,
                                              float* __restrict__ C) {
    const int b  = blockIdx.y;
    const int m0 = (blockIdx.x >> 2) * 64;
    const int n0 = (blockIdx.x & 3) * 64;
    const float* Ab = A + (size_t)b * DD * DD;
    const float* Bb = B + (size_t)b * DD * DD;

    __shared__ float As[64][64];
    __shared__ float Bsh[64][64];

    const int tid  = threadIdx.x;
    const int ty   = tid >> 4;
    const int tx   = tid & 15;
    const int lrow = tid >> 4;
    const int lcol = (tid & 15) * 4;

    float acc[4][4];
#pragma unroll
    for (int i = 0; i < 4; ++i)
#pragma unroll
        for (int j = 0; j < 4; ++j) acc[i][j] = 0.0f;

    for (int k0 = 0; k0 < DD; k0 += 64) {
#pragma unroll
        for (int t = 0; t < 4; ++t) {
            const int row = lrow + t * 16;
            float4 va = *(const float4*)&Ab[(size_t)(k0 + row) * DD + m0 + lcol];
            if (TA == 1) {
                const int gk = k0 + row, gm = m0 + lcol;
                va.x = ((gk == gm + 0) ? 1.5f : 0.0f) - 0.5f * va.x;
                va.y = ((gk == gm + 1) ? 1.5f : 0.0f) - 0.5f * va.y;
                va.z = ((gk == gm + 2) ? 1.5f : 0.0f) - 0.5f * va.z;
                va.w = ((gk == gm + 3) ? 1.5f : 0.0f) - 0.5f * va.w;
            }
            *(float4*)&As[row][lcol] = va;

            float4 vb = *(const float4*)&Bb[(size_t)(k0 + row) * DD + n0 + lcol];
            if (TB == 1) {
                const int gk = k0 + row, gn = n0 + lcol;
                vb.x = ((gk == gn + 0) ? 1.5f : 0.0f) - 0.5f * vb.x;
                vb.y = ((gk == gn + 1) ? 1.5f : 0.0f) - 0.5f * vb.y;
                vb.z = ((gk == gn + 2) ? 1.5f : 0.0f) - 0.5f * vb.z;
                vb.w = ((gk == gn + 3) ? 1.5f : 0.0f) - 0.5f * vb.w;
            }
            *(float4*)&Bsh[row][lcol] = vb;
        }
        __syncthreads();
#pragma unroll 8
        for (int kk = 0; kk < 64; ++kk) {
            const float4 av = *(const float4*)&As[kk][ty * 4];
            const float4 bv = *(const float4*)&Bsh[kk][tx * 4];
            const float a4[4] = {av.x, av.y, av.z, av.w};
            const float b4[4] = {bv.x, bv.y, bv.z, bv.w};
#pragma unroll
            for (int i = 0; i < 4; ++i)
#pragma unroll
                for (int j = 0; j < 4; ++j) acc[i][j] += a4[i] * b4[j];
        }
        __syncthreads();
    }

    float* Cb = C + (size_t)b * DD * DD;
#pragma unroll
    for (int i = 0; i < 4; ++i) {
        float4 vv = make_float4(acc[i][0], acc[i][1], acc[i][2], acc[i][3]);
        *(float4*)&Cb[(size_t)(m0 + ty * 4 + i) * DD + n0 + tx * 4] = vv;
    }
}

// ---------------------------------------------------------------------------
// apply: out[b,s,e] = sum_d (x[b,s,d]-m[b,d]) * wm[b,d,e],  wm = P*rsqrt(tr).
// bf16 MFMA. wm symmetric -> B fragment reads wm rows (k-contiguous, no transpose).
// Grid (64 s-tiles, 2 n-halves, 16 b) x 256 thr; 128x128 tile, K=256.
// B-slab (128 n-rows x 256 k, bf16, +4 pad) staged once; A per k-step of 32.
// ---------------------------------------------------------------------------
#define BSS 260
__global__ __launch_bounds__(256) void apply_kernel(const float* __restrict__ x,
                                                    const float* __restrict__ P,
                                                    const float* __restrict__ m,
                                                    const float* __restrict__ trbuf,
                                                    float* __restrict__ out) {
    const int st = blockIdx.x;
    const int nh = blockIdx.y;
    const int b  = blockIdx.z;
    const int s0 = st * 128;
    const int n0 = nh * 128;
    const float rs = trbuf[16 + b];
    const float* xb = x + (size_t)b * SS * DD;
    const float* Pb = P + (size_t)b * DD * DD;
    const float* mb = m + b * DD;
    float* ob = out + (size_t)b * SS * DD;

    __shared__ unsigned short Bs[128 * BSS];   // 66.6 KB
    __shared__ unsigned short As[128 * LTS];   // 9.2 KB

    const int tid  = threadIdx.x;
    const int wave = tid >> 6;
    const int lane = tid & 63;
    const int lc = lane & 15, lq = lane >> 4;
    const int mrow0 = (wave & 1) * 64;
    const int ncol0 = (wave >> 1) * 64;

    {   // stage B once (rs folded in); wm[k][n]=wm[n][k] by symmetry
        const int r = tid >> 1, h = tid & 1;
        const float* prow = Pb + (size_t)(n0 + r) * DD + h * 128;
        unsigned short* brow = &Bs[r * BSS + h * 128];
#pragma unroll
        for (int i = 0; i < 32; ++i) {
            float4 pv = *(const float4*)(prow + i * 4);
            *(unsigned*)&brow[i * 4]     = pack2(pv.x * rs, pv.y * rs);
            *(unsigned*)&brow[i * 4 + 2] = pack2(pv.z * rs, pv.w * rs);
        }
    }
    __syncthreads();

    f32x4 acc[4][4];
#pragma unroll
    for (int mi = 0; mi < 4; ++mi)
#pragma unroll
        for (int ni = 0; ni < 4; ++ni) acc[mi][ni] = (f32x4){0.f, 0.f, 0.f, 0.f};

    const int r8 = tid >> 3;          // 0..31
    const int d4 = (tid & 7) * 4;

    for (int k0 = 0; k0 < DD; k0 += 32) {
        float4 vv[4];
        const float4 mm = *(const float4*)(mb + k0 + d4);
#pragma unroll
        for (int i = 0; i < 4; ++i) {
            const int r = r8 + i * 32;
            float4 t = *(const float4*)(xb + (size_t)(s0 + r) * DD + k0 + d4);
            t.x -= mm.x; t.y -= mm.y; t.z -= mm.z; t.w -= mm.w;
            vv[i] = t;
        }
        __syncthreads();   // previous step's A-frag reads done
#pragma unroll
        for (int i = 0; i < 4; ++i) {
            unsigned short* arow = &As[(r8 + i * 32) * LTS + d4];
            *(unsigned*)&arow[0] = pack2(vv[i].x, vv[i].y);
            *(unsigned*)&arow[2] = pack2(vv[i].z, vv[i].w);
        }
        __syncthreads();

        bf16x8 af[4], bfr[4];
#pragma unroll
        for (int mi = 0; mi < 4; ++mi)
            af[mi] = ldfrag(&As[(mrow0 + mi * 16 + lc) * LTS + lq * 8]);
#pragma unroll
        for (int ni = 0; ni < 4; ++ni)
            bfr[ni] = ldfrag(&Bs[(ncol0 + ni * 16 + lc) * BSS + k0 + lq * 8]);
#pragma unroll
        for (int mi = 0; mi < 4; ++mi)
#pragma unroll
            for (int ni = 0; ni < 4; ++ni)
                acc[mi][ni] = __builtin_amdgcn_mfma_f32_16x16x32_bf16(
                    af[mi], bfr[ni], acc[mi][ni], 0, 0, 0);
    }

#pragma unroll
    for (int mi = 0; mi < 4; ++mi)
#pragma unroll
        for (int ni = 0; ni < 4; ++ni) {
            const int row = s0 + mrow0 + mi * 16 + lq * 4;
            const int col = n0 + ncol0 + ni * 16 + lc;
#pragma unroll
            for (int r = 0; r < 4; ++r)
                ob[(size_t)(row + r) * DD + col] = acc[mi][ni][r];
        }
}

extern "C" void kernel_launch(void* const* d_in, const int* in_sizes, int n_in,
                              void* d_out, int out_size, void* d_ws, size_t ws_size,
                              hipStream_t stream) {
    const float* x = (const float*)d_in[0];
    float* out = (float*)d_out;
    float* ws = (float*)d_ws;

    const size_t MAT = (size_t)BB * DD * DD;        // 1,048,576 floats
    float* partial = ws;                            // 8 * MAT = 32 MB
    float* sumx  = partial + 8 * MAT;               // 4096
    float* m     = sumx + BB * DD;                  // 4096
    float* trbuf = m + BB * DD;                     // 64
    float* Xa    = trbuf + 64;
    float* Xb    = Xa + MAT;
    float* T     = Xb + MAT;
    float* Pa    = T + MAT;
    float* Pb    = Pa + MAT;
    // total ~54.6 MB of workspace

    hipMemsetAsync(sumx, 0, (size_t)BB * DD * sizeof(float), stream);

    moment_kernel<<<dim3(8, 2, 16), 256, 0, stream>>>(x, partial, sumx);
    stats_kernel<<<16, 256, 0, stream>>>(partial, sumx, m, trbuf);
    sigman_kernel<<<dim3(256, 16), 256, 0, stream>>>(partial, m, trbuf, Xa);

    // Newton-Schulz, commutative form: X0 = sigma_n (in Xa), P1 = W0 (implicit)
    bmm_ns<1, 1><<<dim3(16, 16), 256, 0, stream>>>(Xa, Xa, T);   // T  = W0^2
    bmm_ns<0, 0><<<dim3(16, 16), 256, 0, stream>>>(Xa, T, Xb);   // X1 = X0*W0^2
    bmm_ns<1, 1><<<dim3(16, 16), 256, 0, stream>>>(Xa, Xb, Pa);  // P2 = W0*W1
    bmm_ns<1, 1><<<dim3(16, 16), 256, 0, stream>>>(Xb, Xb, T);   // T  = W1^2
    bmm_ns<0, 0><<<dim3(16, 16), 256, 0, stream>>>(Xb, T, Xa);   // X2 = X1*W1^2
    bmm_ns<0, 1><<<dim3(16, 16), 256, 0, stream>>>(Pa, Xa, Pb);  // P3 = P2*W2
    bmm_ns<1, 1><<<dim3(16, 16), 256, 0, stream>>>(Xa, Xa, T);   // T  = W2^2
    bmm_ns<0, 0><<<dim3(16, 16), 256, 0, stream>>>(Xa, T, Xb);   // X3 = X2*W2^2
    bmm_ns<0, 1><<<dim3(16, 16), 256, 0, stream>>>(Pb, Xb, Pa);  // P4 = P3*W3

    apply_kernel<<<dim3(64, 2, 16), 256, 0, stream>>>(x, Pa, m, trbuf, out);
}